// Round 10
// baseline (363.145 us; speedup 1.0000x reference)
//
#include <hip/hip_runtime.h>
#include <hip/hip_bf16.h>

#define NPTS 1048576
#define NCLU 16384
#define DF   64
#define H1   128
#define H2   64
#define BP   64        // points per tile
#define NBLK 1024      // persistent blocks (2 per CU)
#define ITERS (NPTS / (BP * NBLK))   // 16 contiguous tiles per block (even)
#define K1P  104       // LDS row stride (u16) for K=96 (67 valid + zero pad)
#define K2P  136       // LDS row stride (u16) for K=128

typedef __bf16 bf16x8 __attribute__((ext_vector_type(8)));
typedef float  f32x4  __attribute__((ext_vector_type(4)));
typedef unsigned short u16x4 __attribute__((ext_vector_type(4)));
typedef unsigned short u16x8 __attribute__((ext_vector_type(8)));

__device__ __forceinline__ unsigned short f2b(float f) {
  unsigned v; __builtin_memcpy(&v, &f, 4);
  v += 0x7fffu + ((v >> 16) & 1u);          // round-to-nearest-even
  return (unsigned short)(v >> 16);
}

// pre-kernel: feat fp32 [16384][64] -> bf16 u16 same layout in ws
__global__ __launch_bounds__(256, 4)
void cvt_feat(const float* __restrict__ f, unsigned short* __restrict__ o) {
  int i = (blockIdx.x * 256 + threadIdx.x) * 4;
  f32x4 v = *(const f32x4*)&f[i];
  u16x4 h;
  #pragma unroll
  for (int j = 0; j < 4; ++j) h[j] = f2b(v[j]);
  *(u16x4*)&o[i] = h;
}

__device__ __forceinline__ void load_labels(const int* __restrict__ labels, int off,
                                            int lane, int rowA, int rowB,
                                            int& lA, int& lB, int& lD) {
  lA = labels[off + rowA];
  lB = labels[off + rowB];
  lD = (lane < 16) ? labels[off + lane] : 0;
}

__device__ __forceinline__ void load_payload(const unsigned short* __restrict__ featbf,
                                             const float* __restrict__ feat,
                                             const float* __restrict__ centers,
                                             const float* __restrict__ points,
                                             int use_bf, int lane, int kc8, int rowOff,
                                             int lA, int lB, int lD,
                                             u16x8& gA, u16x8& gB, u16x8& hD) {
  if (use_bf) {
    gA = *(const u16x8*)&featbf[lA * DF + kc8];
    gB = *(const u16x8*)&featbf[lB * DF + kc8];
  } else {
    f32x4 a0 = *(const f32x4*)&feat[lA * DF + kc8];
    f32x4 a1 = *(const f32x4*)&feat[lA * DF + kc8 + 4];
    f32x4 b0 = *(const f32x4*)&feat[lB * DF + kc8];
    f32x4 b1x = *(const f32x4*)&feat[lB * DF + kc8 + 4];
    #pragma unroll
    for (int j = 0; j < 4; ++j) {
      gA[j] = f2b(a0[j]); gA[j + 4] = f2b(a1[j]);
      gB[j] = f2b(b0[j]); gB[j + 4] = f2b(b1x[j]);
    }
  }
  hD = (u16x8){0, 0, 0, 0, 0, 0, 0, 0};
  if (lane < 16) {
    long p = rowOff + lane;
    #pragma unroll
    for (int j = 0; j < 3; ++j) hD[j] = f2b(centers[lD * 3 + j] - points[p * 3 + j]);
  }
}

// R9 structure + 2-deep pipeline: loop unrolled x2 with named payload stages
// X/Y (no runtime-indexed reg arrays) so each payload's gather loads get TWO
// compute phases (~1000 cyc) before the commit-wait -> covers full HBM-miss
// latency. Labels run 2 stages ahead of payloads. VGPR headroom is free
// (LDS caps occupancy at 2 blocks/CU regardless).
__global__ __launch_bounds__(256, 2)
void fused_gather_mlp(const float* __restrict__ feat,
                      const int* __restrict__ labels,
                      const float* __restrict__ centers,
                      const float* __restrict__ points,
                      const float* __restrict__ W1,
                      const float* __restrict__ b1,
                      const float* __restrict__ W2,
                      const float* __restrict__ b2,
                      float* __restrict__ out,
                      const unsigned short* __restrict__ featbf,
                      int use_bf)
{
  __shared__ __align__(16) unsigned short sX[BP][K1P];   // x tile bf16 (wave-private rows)
  __shared__ __align__(16) unsigned short sW1[H1][K1P];  // W1^T bf16 [n][k]
  __shared__ __align__(16) unsigned short sH[BP][K2P];   // hidden bf16 (wave-private rows)
  __shared__ __align__(16) unsigned short sW2[H2][K2P];  // W2^T bf16 [n][k]
  __shared__ __align__(16) float sB1[H1];

  const int t    = threadIdx.x;
  const int w    = t >> 6;
  const int lane = t & 63;
  const int quad = lane >> 4, l16 = lane & 15;
  const int m0   = w * 16;                 // this wave's 16-row M tile
  const int rowA = lane >> 3;              // gather row for task 0 (rows 0..7)
  const int rowB = rowA + 8;               // gather row for task 1 (rows 8..15)
  const int kc8  = (lane & 7) * 8;         // u16 column offset within the row

  // ---------------- one-time staging (conflict-free, chunk-granular) ----------------
  if (t < 32) *(f32x4*)&sB1[t * 4] = *(const f32x4*)&b1[t * 4];

  // W1 [67][128] -> sW1[n][k]
  #pragma unroll
  for (int i = 0; i < 6; ++i) {            // 128 n * 12 kc = 1536 tasks
    int task = t + 256 * i;
    int n = task & 127, kc = task >> 7;
    u16x8 h;
    #pragma unroll
    for (int j = 0; j < 8; ++j) {
      int k = kc * 8 + j;
      float v = (k < 67) ? W1[k * H1 + n] : 0.f;
      h[j] = f2b(v);
    }
    *(u16x8*)&sW1[n][kc * 8] = h;
  }
  // W2 [128][64] -> sW2[n][k]
  #pragma unroll
  for (int i = 0; i < 4; ++i) {            // 64 n * 16 kc = 1024 tasks
    int task = t + 256 * i;
    int n = task & 63, kc = task >> 6;
    u16x8 h;
    #pragma unroll
    for (int j = 0; j < 8; ++j) h[j] = f2b(W2[(kc * 8 + j) * H2 + n]);
    *(u16x8*)&sW2[n][kc * 8] = h;
  }
  // zero this wave's sX pad chunks 9..11 (k=72..95) once; chunk 8 rewritten every iter
  if (lane < 48) {
    int r = lane & 15, c = 9 + (lane >> 4);
    u16x8 z = {0, 0, 0, 0, 0, 0, 0, 0};
    *(u16x8*)&sX[m0 + r][c * 8] = z;
  }

  // bias2 as accumulator-init: acc2[nt2][r] <-> n2 = nt2*16+quad*4+r
  f32x4 bias2v[4];
  #pragma unroll
  for (int nt2 = 0; nt2 < 4; ++nt2)
    bias2v[nt2] = *(const f32x4*)&b2[nt2 * 16 + quad * 4];

  __syncthreads();                         // the ONLY barrier

  // hoist per-lane bias1 (loop-invariant; epi1 column n = nt*16+l16)
  float bias1[8];
  #pragma unroll
  for (int nt = 0; nt < 8; ++nt) bias1[nt] = sB1[nt * 16 + l16];

  const int base = blockIdx.x * ITERS;

  // ---------------- 2-deep pipeline prologue ----------------
  u16x8 gXa, gXb, hXd;                     // stage X: payload(even tile)
  u16x8 gYa, gYb, hYd;                     // stage Y: payload(odd tile)
  int lPa, lPb, lPd;                       // labels for next X refill
  int lQa, lQb, lQd;                       // labels for next Y refill
  {
    int la, lb, ld;
    load_labels(labels, base * BP + m0, lane, rowA, rowB, la, lb, ld);
    load_payload(featbf, feat, centers, points, use_bf, lane, kc8,
                 base * BP + m0, la, lb, ld, gXa, gXb, hXd);          // payload(0)
    int i1 = (1 < ITERS) ? 1 : ITERS - 1;
    load_labels(labels, (base + i1) * BP + m0, lane, rowA, rowB, la, lb, ld);
    load_payload(featbf, feat, centers, points, use_bf, lane, kc8,
                 (base + i1) * BP + m0, la, lb, ld, gYa, gYb, hYd);   // payload(1)
    int i2 = (2 < ITERS) ? 2 : ITERS - 1;
    int i3 = (3 < ITERS) ? 3 : ITERS - 1;
    load_labels(labels, (base + i2) * BP + m0, lane, rowA, rowB, lPa, lPb, lPd);
    load_labels(labels, (base + i3) * BP + m0, lane, rowA, rowB, lQa, lQb, lQd);
  }

  // ---------------- main loop, unrolled x2 (ITERS even) ----------------
  for (int it = 0; it < ITERS; it += 2) {
    // ======== sub-iteration A: tile it (stage X) ========
    {
      const int p0 = (base + it) * BP;
      // commit payload(it) regs -> LDS
      *(u16x8*)&sX[m0 + rowA][kc8] = gXa;
      *(u16x8*)&sX[m0 + rowB][kc8] = gXb;
      if (lane < 16) *(u16x8*)&sX[m0 + lane][DF] = hXd;
      // refill X with payload(it+2) (in flight across 2 compute phases)
      const int i2 = (it + 2 < ITERS) ? it + 2 : ITERS - 1;
      load_payload(featbf, feat, centers, points, use_bf, lane, kc8,
                   (base + i2) * BP + m0, lPa, lPb, lPd, gXa, gXb, hXd);
      // advance P labels to it+4
      const int i4 = (it + 4 < ITERS) ? it + 4 : ITERS - 1;
      load_labels(labels, (base + i4) * BP + m0, lane, rowA, rowB, lPa, lPb, lPd);

      // GEMM1: [16,96] x [96,128]
      f32x4 acc[8];
      #pragma unroll
      for (int i = 0; i < 8; ++i) acc[i] = (f32x4){0.f, 0.f, 0.f, 0.f};
      #pragma unroll
      for (int ks = 0; ks < 3; ++ks) {
        int k0 = ks * 32 + quad * 8;
        bf16x8 a = *(const bf16x8*)&sX[m0 + l16][k0];
        #pragma unroll
        for (int nt = 0; nt < 8; ++nt) {
          bf16x8 b = *(const bf16x8*)&sW1[nt * 16 + l16][k0];
          acc[nt] = __builtin_amdgcn_mfma_f32_16x16x32_bf16(a, b, acc[nt], 0, 0, 0);
        }
      }
      #pragma unroll
      for (int nt = 0; nt < 8; ++nt) {
        int n = nt * 16 + l16;
        #pragma unroll
        for (int r = 0; r < 4; ++r) {
          float v = acc[nt][r] + bias1[nt];
          v = v > 0.f ? v : 0.f;
          sH[m0 + quad * 4 + r][n] = f2b(v);
        }
      }
      // GEMM2 (swapped)
      f32x4 acc2[4];
      #pragma unroll
      for (int i = 0; i < 4; ++i) acc2[i] = bias2v[i];
      #pragma unroll
      for (int ks = 0; ks < 4; ++ks) {
        int k0 = ks * 32 + quad * 8;
        bf16x8 hf = *(const bf16x8*)&sH[m0 + l16][k0];
        #pragma unroll
        for (int nt2 = 0; nt2 < 4; ++nt2) {
          bf16x8 wf = *(const bf16x8*)&sW2[nt2 * 16 + l16][k0];
          acc2[nt2] = __builtin_amdgcn_mfma_f32_16x16x32_bf16(wf, hf, acc2[nt2], 0, 0, 0);
        }
      }
      const long prow = (long)(p0 + m0 + l16) * H2;
      #pragma unroll
      for (int nt2 = 0; nt2 < 4; ++nt2) {
        f32x4 v = acc2[nt2];
        #pragma unroll
        for (int r = 0; r < 4; ++r) v[r] = v[r] > 0.f ? v[r] : 0.f;
        *(f32x4*)&out[prow + nt2 * 16 + quad * 4] = v;
      }
    }

    // ======== sub-iteration B: tile it+1 (stage Y) ========
    {
      const int p0 = (base + it + 1) * BP;
      // commit payload(it+1) regs -> LDS
      *(u16x8*)&sX[m0 + rowA][kc8] = gYa;
      *(u16x8*)&sX[m0 + rowB][kc8] = gYb;
      if (lane < 16) *(u16x8*)&sX[m0 + lane][DF] = hYd;
      // refill Y with payload(it+3)
      const int i3 = (it + 3 < ITERS) ? it + 3 : ITERS - 1;
      load_payload(featbf, feat, centers, points, use_bf, lane, kc8,
                   (base + i3) * BP + m0, lQa, lQb, lQd, gYa, gYb, hYd);
      // advance Q labels to it+5
      const int i5 = (it + 5 < ITERS) ? it + 5 : ITERS - 1;
      load_labels(labels, (base + i5) * BP + m0, lane, rowA, rowB, lQa, lQb, lQd);

      // GEMM1
      f32x4 acc[8];
      #pragma unroll
      for (int i = 0; i < 8; ++i) acc[i] = (f32x4){0.f, 0.f, 0.f, 0.f};
      #pragma unroll
      for (int ks = 0; ks < 3; ++ks) {
        int k0 = ks * 32 + quad * 8;
        bf16x8 a = *(const bf16x8*)&sX[m0 + l16][k0];
        #pragma unroll
        for (int nt = 0; nt < 8; ++nt) {
          bf16x8 b = *(const bf16x8*)&sW1[nt * 16 + l16][k0];
          acc[nt] = __builtin_amdgcn_mfma_f32_16x16x32_bf16(a, b, acc[nt], 0, 0, 0);
        }
      }
      #pragma unroll
      for (int nt = 0; nt < 8; ++nt) {
        int n = nt * 16 + l16;
        #pragma unroll
        for (int r = 0; r < 4; ++r) {
          float v = acc[nt][r] + bias1[nt];
          v = v > 0.f ? v : 0.f;
          sH[m0 + quad * 4 + r][n] = f2b(v);
        }
      }
      // GEMM2 (swapped)
      f32x4 acc2[4];
      #pragma unroll
      for (int i = 0; i < 4; ++i) acc2[i] = bias2v[i];
      #pragma unroll
      for (int ks = 0; ks < 4; ++ks) {
        int k0 = ks * 32 + quad * 8;
        bf16x8 hf = *(const bf16x8*)&sH[m0 + l16][k0];
        #pragma unroll
        for (int nt2 = 0; nt2 < 4; ++nt2) {
          bf16x8 wf = *(const bf16x8*)&sW2[nt2 * 16 + l16][k0];
          acc2[nt2] = __builtin_amdgcn_mfma_f32_16x16x32_bf16(wf, hf, acc2[nt2], 0, 0, 0);
        }
      }
      const long prow = (long)(p0 + m0 + l16) * H2;
      #pragma unroll
      for (int nt2 = 0; nt2 < 4; ++nt2) {
        f32x4 v = acc2[nt2];
        #pragma unroll
        for (int r = 0; r < 4; ++r) v[r] = v[r] > 0.f ? v[r] : 0.f;
        *(f32x4*)&out[prow + nt2 * 16 + quad * 4] = v;
      }
    }
  }
}

extern "C" void kernel_launch(void* const* d_in, const int* in_sizes, int n_in,
                              void* d_out, int out_size, void* d_ws, size_t ws_size,
                              hipStream_t stream) {
  const float* feat   = (const float*)d_in[0];
  const int*   labels = (const int*)d_in[1];
  const float* cen    = (const float*)d_in[2];
  const float* pts    = (const float*)d_in[3];
  const float* W1     = (const float*)d_in[4];
  const float* b1     = (const float*)d_in[5];
  const float* W2     = (const float*)d_in[6];
  const float* b2     = (const float*)d_in[7];
  float*       outp   = (float*)d_out;

  const size_t featbf_bytes = (size_t)NCLU * DF * sizeof(unsigned short);  // 2 MB
  int use_bf = (ws_size >= featbf_bytes) ? 1 : 0;
  unsigned short* featbf = (unsigned short*)d_ws;

  if (use_bf)
    cvt_feat<<<dim3(NCLU * DF / (256 * 4)), dim3(256), 0, stream>>>(feat, featbf);

  fused_gather_mlp<<<dim3(NBLK), dim3(256), 0, stream>>>(
      feat, labels, cen, pts, W1, b1, W2, b2, outp, featbf, use_bf);
}

// Round 11
// 350.040 us; speedup vs baseline: 1.0374x; 1.0374x over previous
//
#include <hip/hip_runtime.h>
#include <hip/hip_bf16.h>

#define NPTS 1048576
#define NCLU 16384
#define DF   64
#define H1   128
#define H2   64
#define BP   64        // points per tile
#define NBLK 1024      // persistent blocks (2 per CU)
#define ITERS (NPTS / (BP * NBLK))   // 16 contiguous tiles per block
#define K1P  104       // LDS row stride (u16) for K=96 (67 valid + zero pad)
#define K2P  136       // LDS row stride (u16) for K=128

typedef __bf16 bf16x8 __attribute__((ext_vector_type(8)));
typedef float  f32x4  __attribute__((ext_vector_type(4)));
typedef unsigned short u16x4 __attribute__((ext_vector_type(4)));
typedef unsigned short u16x8 __attribute__((ext_vector_type(8)));

__device__ __forceinline__ unsigned short f2b(float f) {
  unsigned v; __builtin_memcpy(&v, &f, 4);
  v += 0x7fffu + ((v >> 16) & 1u);          // round-to-nearest-even
  return (unsigned short)(v >> 16);
}

// pre-kernel: feat fp32 [16384][64] -> bf16 u16 same layout in ws
__global__ __launch_bounds__(256, 4)
void cvt_feat(const float* __restrict__ f, unsigned short* __restrict__ o) {
  int i = (blockIdx.x * 256 + threadIdx.x) * 4;
  f32x4 v = *(const f32x4*)&f[i];
  u16x4 h;
  #pragma unroll
  for (int j = 0; j < 4; ++j) h[j] = f2b(v[j]);
  *(u16x4*)&o[i] = h;
}

// SESSION-BEST configuration (R9, 353.0 us): R1-proven loop structure
// (contiguous 16-tile chunks, 2 blocks/CU, LDS-resident W1/W2, no
// per-iteration barriers) + swapped-operand GEMM2 (coalesced dwordx4 stores,
// bias2 as acc-init) + T14 depth-1 async-STAGE split: tile t's gather payload
// enters the iteration in REGISTERS; regs->LDS commit is vmcnt-free, and tile
// t+1's global loads issue before compute so GEMM1/GEMM2 hide their latency.
// Labels pipelined 2 tiles ahead, payload 1 tile ahead.
// (Depth-2 pipeline measured REGRESSION in R10: +reg pressure, no gain.)
__global__ __launch_bounds__(256, 2)
void fused_gather_mlp(const float* __restrict__ feat,
                      const int* __restrict__ labels,
                      const float* __restrict__ centers,
                      const float* __restrict__ points,
                      const float* __restrict__ W1,
                      const float* __restrict__ b1,
                      const float* __restrict__ W2,
                      const float* __restrict__ b2,
                      float* __restrict__ out,
                      const unsigned short* __restrict__ featbf,
                      int use_bf)
{
  __shared__ __align__(16) unsigned short sX[BP][K1P];   // x tile bf16 (wave-private rows)
  __shared__ __align__(16) unsigned short sW1[H1][K1P];  // W1^T bf16 [n][k]
  __shared__ __align__(16) unsigned short sH[BP][K2P];   // hidden bf16 (wave-private rows)
  __shared__ __align__(16) unsigned short sW2[H2][K2P];  // W2^T bf16 [n][k]
  __shared__ __align__(16) float sB1[H1];

  const int t    = threadIdx.x;
  const int w    = t >> 6;
  const int lane = t & 63;
  const int quad = lane >> 4, l16 = lane & 15;
  const int m0   = w * 16;                 // this wave's 16-row M tile
  const int rowA = lane >> 3;              // gather row for task 0 (rows 0..7)
  const int rowB = rowA + 8;               // gather row for task 1 (rows 8..15)
  const int kc8  = (lane & 7) * 8;         // u16 column offset within the row

  // ---------------- one-time staging (conflict-free, chunk-granular) ----------------
  if (t < 32) *(f32x4*)&sB1[t * 4] = *(const f32x4*)&b1[t * 4];

  // W1 [67][128] -> sW1[n][k]
  #pragma unroll
  for (int i = 0; i < 6; ++i) {            // 128 n * 12 kc = 1536 tasks
    int task = t + 256 * i;
    int n = task & 127, kc = task >> 7;
    u16x8 h;
    #pragma unroll
    for (int j = 0; j < 8; ++j) {
      int k = kc * 8 + j;
      float v = (k < 67) ? W1[k * H1 + n] : 0.f;
      h[j] = f2b(v);
    }
    *(u16x8*)&sW1[n][kc * 8] = h;
  }
  // W2 [128][64] -> sW2[n][k]
  #pragma unroll
  for (int i = 0; i < 4; ++i) {            // 64 n * 16 kc = 1024 tasks
    int task = t + 256 * i;
    int n = task & 63, kc = task >> 6;
    u16x8 h;
    #pragma unroll
    for (int j = 0; j < 8; ++j) h[j] = f2b(W2[(kc * 8 + j) * H2 + n]);
    *(u16x8*)&sW2[n][kc * 8] = h;
  }
  // zero this wave's sX pad chunks 9..11 (k=72..95) once; chunk 8 rewritten every iter
  if (lane < 48) {
    int r = lane & 15, c = 9 + (lane >> 4);
    u16x8 z = {0, 0, 0, 0, 0, 0, 0, 0};
    *(u16x8*)&sX[m0 + r][c * 8] = z;
  }

  // bias2 as accumulator-init: acc2[nt2][r] <-> n2 = nt2*16+quad*4+r (tiny global reads)
  f32x4 bias2v[4];
  #pragma unroll
  for (int nt2 = 0; nt2 < 4; ++nt2)
    bias2v[nt2] = *(const f32x4*)&b2[nt2 * 16 + quad * 4];

  __syncthreads();                         // the ONLY barrier

  // hoist per-lane bias1 (loop-invariant; epi1 column n = nt*16+l16)
  float bias1[8];
  #pragma unroll
  for (int nt = 0; nt < 8; ++nt) bias1[nt] = sB1[nt * 16 + l16];

  const int base = blockIdx.x * ITERS;

  // ---------------- software-pipeline prologue ----------------
  // payload(t0): featbf chunks + chunk-8 diffs, in registers
  u16x8 gA, gB, hD = {0, 0, 0, 0, 0, 0, 0, 0};
  {
    int labA0 = labels[base * BP + m0 + rowA];
    int labB0 = labels[base * BP + m0 + rowB];
    if (use_bf) {
      gA = *(const u16x8*)&featbf[labA0 * DF + kc8];
      gB = *(const u16x8*)&featbf[labB0 * DF + kc8];
    } else {
      f32x4 a0 = *(const f32x4*)&feat[labA0 * DF + kc8];
      f32x4 a1 = *(const f32x4*)&feat[labA0 * DF + kc8 + 4];
      f32x4 b0 = *(const f32x4*)&feat[labB0 * DF + kc8];
      f32x4 b1v = *(const f32x4*)&feat[labB0 * DF + kc8 + 4];
      #pragma unroll
      for (int j = 0; j < 4; ++j) {
        gA[j] = f2b(a0[j]); gA[j + 4] = f2b(a1[j]);
        gB[j] = f2b(b0[j]); gB[j + 4] = f2b(b1v[j]);
      }
    }
    if (lane < 16) {
      int p = base * BP + m0 + lane;
      int labD0 = labels[p];
      #pragma unroll
      for (int j = 0; j < 3; ++j) hD[j] = f2b(centers[labD0 * 3 + j] - points[(long)p * 3 + j]);
    }
  }
  // labels(t1)
  const int tl1 = (ITERS > 1) ? 1 : 0;
  int labA1 = labels[(base + tl1) * BP + m0 + rowA];
  int labB1 = labels[(base + tl1) * BP + m0 + rowB];
  int labD1 = (lane < 16) ? labels[(base + tl1) * BP + m0 + lane] : 0;

  // ---------------- main loop: payload 1 ahead, labels 2 ahead ----------------
  for (int it = 0; it < ITERS; ++it) {
    const int p0 = (base + it) * BP;

    // (1) commit current payload regs -> LDS (no vmcnt dependency)
    *(u16x8*)&sX[m0 + rowA][kc8] = gA;
    *(u16x8*)&sX[m0 + rowB][kc8] = gB;
    if (lane < 16) *(u16x8*)&sX[m0 + lane][DF] = hD;

    // (2) issue payload(t+1) loads now; compute below hides their latency
    const int tn = (it + 1 < ITERS) ? it + 1 : it;      // clamp tail (redundant, correct)
    u16x8 gA1, gB1, hD1 = {0, 0, 0, 0, 0, 0, 0, 0};
    if (use_bf) {
      gA1 = *(const u16x8*)&featbf[labA1 * DF + kc8];
      gB1 = *(const u16x8*)&featbf[labB1 * DF + kc8];
    } else {
      f32x4 a0 = *(const f32x4*)&feat[labA1 * DF + kc8];
      f32x4 a1 = *(const f32x4*)&feat[labA1 * DF + kc8 + 4];
      f32x4 b0 = *(const f32x4*)&feat[labB1 * DF + kc8];
      f32x4 b1v = *(const f32x4*)&feat[labB1 * DF + kc8 + 4];
      #pragma unroll
      for (int j = 0; j < 4; ++j) {
        gA1[j] = f2b(a0[j]); gA1[j + 4] = f2b(a1[j]);
        gB1[j] = f2b(b0[j]); gB1[j + 4] = f2b(b1v[j]);
      }
    }
    if (lane < 16) {
      int pn = (base + tn) * BP + m0 + lane;
      #pragma unroll
      for (int j = 0; j < 3; ++j) hD1[j] = f2b(centers[labD1 * 3 + j] - points[(long)pn * 3 + j]);
    }
    // (3) issue labels(t+2)
    const int t2 = (it + 2 < ITERS) ? it + 2 : ITERS - 1;
    int labA2 = labels[(base + t2) * BP + m0 + rowA];
    int labB2 = labels[(base + t2) * BP + m0 + rowB];
    int labD2 = (lane < 16) ? labels[(base + t2) * BP + m0 + lane] : 0;

    // (4) GEMM1: [16,96] x [96,128]
    f32x4 acc[8];
    #pragma unroll
    for (int i = 0; i < 8; ++i) acc[i] = (f32x4){0.f, 0.f, 0.f, 0.f};
    #pragma unroll
    for (int ks = 0; ks < 3; ++ks) {
      int k0 = ks * 32 + quad * 8;
      bf16x8 a = *(const bf16x8*)&sX[m0 + l16][k0];
      #pragma unroll
      for (int nt = 0; nt < 8; ++nt) {
        bf16x8 b = *(const bf16x8*)&sW1[nt * 16 + l16][k0];
        acc[nt] = __builtin_amdgcn_mfma_f32_16x16x32_bf16(a, b, acc[nt], 0, 0, 0);
      }
    }
    // epilogue 1: bias + relu -> bf16 -> sH (wave-private; C[m=quad*4+r][n=nt*16+l16])
    #pragma unroll
    for (int nt = 0; nt < 8; ++nt) {
      int n = nt * 16 + l16;
      #pragma unroll
      for (int r = 0; r < 4; ++r) {
        float v = acc[nt][r] + bias1[nt];
        v = v > 0.f ? v : 0.f;
        sH[m0 + quad * 4 + r][n] = f2b(v);
      }
    }

    // GEMM2 (swapped): acc2[nt2] = mfma(W2frag, Hfrag) -> lane holds
    // out[m=l16][n2 = nt2*16 + quad*4 + r], 4 contiguous floats per acc block
    f32x4 acc2[4];
    #pragma unroll
    for (int i = 0; i < 4; ++i) acc2[i] = bias2v[i];
    #pragma unroll
    for (int ks = 0; ks < 4; ++ks) {
      int k0 = ks * 32 + quad * 8;
      bf16x8 hf = *(const bf16x8*)&sH[m0 + l16][k0];
      #pragma unroll
      for (int nt2 = 0; nt2 < 4; ++nt2) {
        bf16x8 wf = *(const bf16x8*)&sW2[nt2 * 16 + l16][k0];
        acc2[nt2] = __builtin_amdgcn_mfma_f32_16x16x32_bf16(wf, hf, acc2[nt2], 0, 0, 0);
      }
    }
    // epilogue 2: relu -> 4x coalesced dwordx4 stores (lane owns row m0+l16)
    const long prow = (long)(p0 + m0 + l16) * H2;
    #pragma unroll
    for (int nt2 = 0; nt2 < 4; ++nt2) {
      f32x4 v = acc2[nt2];
      #pragma unroll
      for (int r = 0; r < 4; ++r) v[r] = v[r] > 0.f ? v[r] : 0.f;
      *(f32x4*)&out[prow + nt2 * 16 + quad * 4] = v;
    }

    // (5) rotate pipeline
    gA = gA1; gB = gB1; hD = hD1;
    labA1 = labA2; labB1 = labB2; labD1 = labD2;
  }
}

extern "C" void kernel_launch(void* const* d_in, const int* in_sizes, int n_in,
                              void* d_out, int out_size, void* d_ws, size_t ws_size,
                              hipStream_t stream) {
  const float* feat   = (const float*)d_in[0];
  const int*   labels = (const int*)d_in[1];
  const float* cen    = (const float*)d_in[2];
  const float* pts    = (const float*)d_in[3];
  const float* W1     = (const float*)d_in[4];
  const float* b1     = (const float*)d_in[5];
  const float* W2     = (const float*)d_in[6];
  const float* b2     = (const float*)d_in[7];
  float*       outp   = (float*)d_out;

  const size_t featbf_bytes = (size_t)NCLU * DF * sizeof(unsigned short);  // 2 MB
  int use_bf = (ws_size >= featbf_bytes) ? 1 : 0;
  unsigned short* featbf = (unsigned short*)d_ws;

  if (use_bf)
    cvt_feat<<<dim3(NCLU * DF / (256 * 4)), dim3(256), 0, stream>>>(feat, featbf);

  fused_gather_mlp<<<dim3(NBLK), dim3(256), 0, stream>>>(
      feat, labels, cen, pts, W1, b1, W2, b2, outp, featbf, use_bf);
}